// Round 14
// baseline (6296.741 us; speedup 1.0000x reference)
//
#include <hip/hip_runtime.h>
#include <hip/hip_bf16.h>
#include <stdint.h>

#define T_LEN 4096
#define D_DIM 256
#define HDIM 256
#define G4 1024          // 4*HD gate rows per direction
#define NTAGS 32
#define START_TAG 30
#define STOP_TAG 31

typedef unsigned long long u64;
typedef unsigned int u32;

__device__ __forceinline__ float sigf(float x){ return 1.0f/(1.0f+expf(-x)); }

// ---------------------------------------------------------------------------
// K1: embedding gather + input projections (r6-exact 4096-block version).
// ---------------------------------------------------------------------------
__global__ __launch_bounds__(256) void k_xg(const int* __restrict__ seq,
    const float* __restrict__ E,
    const float* __restrict__ Wf, const float* __restrict__ bihf, const float* __restrict__ bhhf,
    const float* __restrict__ Wb, const float* __restrict__ bihb, const float* __restrict__ bhhb,
    float* __restrict__ xg_f, float* __restrict__ xg_b)
{
    __shared__ __align__(16) float xsh[8][D_DIM];
    __shared__ int sq[8];
    const int b = blockIdx.x, tb = b >> 3, cb = b & 7, j = threadIdx.x;
    if (j < 8) sq[j] = seq[tb*8 + j];
    __syncthreads();
    #pragma unroll
    for (int r = 0; r < 8; ++r) xsh[r][j] = E[(size_t)sq[r]*D_DIM + j];
    __syncthreads();
    const int col = cb*256 + j;      // 0..2047
    const int d   = col >> 10;       // 0 fwd, 1 bwd
    const int row = col & 1023;
    const float* W = d ? Wb : Wf;
    const float bias = d ? (bihb[row] + bhhb[row]) : (bihf[row] + bhhf[row]);
    const float4* wr = reinterpret_cast<const float4*>(W + (size_t)row*D_DIM);
    float acc[8];
    #pragma unroll
    for (int r=0;r<8;++r) acc[r] = 0.f;
    for (int kk = 0; kk < D_DIM/4; ++kk){
        float4 wv = wr[kk];
        #pragma unroll
        for (int r=0;r<8;++r){
            float4 xv = reinterpret_cast<const float4*>(xsh[r])[kk];
            acc[r] = fmaf(wv.x, xv.x, fmaf(wv.y, xv.y, fmaf(wv.z, xv.z, fmaf(wv.w, xv.w, acc[r]))));
        }
    }
    #pragma unroll
    for (int r=0;r<8;++r){
        const int t = tb*8 + r;
        const float v = acc[r] + bias;
        if (d == 0) xg_f[(size_t)t*G4 + row] = v;
        else        xg_b[(size_t)(T_LEN-1-t)*G4 + row] = v;
    }
}

// ---------------------------------------------------------------------------
// K2: bidirectional LSTM — r6 skeleton (the established local optimum) with
// ONE change: DOUBLE-PUMPED POLL. Two outstanding loads to the tag slot,
// checked alternately (compiler emits load a; load b; vmcnt(1); chk; vmcnt(0);
// chk) -> sampling period halves -> expected detection latency improves by
// ~RT/2. Falsifiable probe of detection-limited vs visibility-limited
// exchange. Values unaffected (tags gate exact data).
// ---------------------------------------------------------------------------
__global__ __launch_bounds__(256,1) void k_lstm(
    const float* __restrict__ Whh_f, const float* __restrict__ Whh_b,
    const float* __restrict__ xgf, const float* __restrict__ xgb,
    const float* __restrict__ h0, const float* __restrict__ c0,
    float* __restrict__ hs_f, float* __restrict__ hs_b,
    u64* __restrict__ hbuf_all)
{
    const int blk = blockIdx.x;       // 0..63
    const int d   = blk >> 5;         // direction
    const int sb  = blk & 31;         // sub-block within direction
    const int ulo = sb * 8;           // first owned unit
    const int j = threadIdx.x;        // 0..255
    const int r = j & 31;             // row_local in [0,32)
    const int o = j >> 5;             // k-slice (32 k each)
    const int g_r = r >> 3;           // gate of this row
    const int u_r = r & 7;            // unit offset
    const int row_global = g_r*256 + ulo + u_r;   // in [0,1024)

    const float* __restrict__ Whh = d ? Whh_b : Whh_f;
    const float* __restrict__ xg  = d ? xgb : xgf;
    float* __restrict__ hs = d ? hs_b : hs_f;
    u64* __restrict__ hb = hbuf_all + (size_t)d*2*HDIM;   // [parity][unit]

    __shared__ __align__(16) char wbuf[32*1024];  // [r][k] f32, swizzled
    __shared__ float h_sh[HDIM];                  // wave w owns [64w,64w+64)
    __shared__ float partial[2*256];              // [parity][o][r]

    // ---- stage weights (thread stages exactly its read set) ----
    {
        const float4* src = reinterpret_cast<const float4*>(Whh + (size_t)row_global*HDIM + o*32);
        #pragma unroll
        for (int i = 0; i < 8; ++i){
            *reinterpret_cast<float4*>(wbuf + ((r*1024 + (o*8+i)*16) ^ ((r&7)<<4))) = src[i];
        }
    }
    h_sh[j] = h0[d*HDIM + j];
    float c = (j < 8) ? c0[d*HDIM + ulo + j] : 0.0f;
    float xgc = xg[row_global];       // xg[0][row]
    __syncthreads();

    for (int t = 0; t < T_LEN; ++t){
        const int par = t & 1;
        if (t > 0){
            // double-pumped poll of unit j (tag t)
            const u32 want = (u32)t;
            u64* p = &hb[(size_t)par*HDIM + j];
            u64 pk;
            u64 a = __hip_atomic_load(p, __ATOMIC_RELAXED, __HIP_MEMORY_SCOPE_AGENT);
            u64 b = __hip_atomic_load(p, __ATOMIC_RELAXED, __HIP_MEMORY_SCOPE_AGENT);
            for (;;){
                if ((u32)(a >> 32) == want){ pk = a; break; }
                if ((u32)(b >> 32) == want){ pk = b; break; }
                a = __hip_atomic_load(p, __ATOMIC_RELAXED, __HIP_MEMORY_SCOPE_AGENT);
                b = __hip_atomic_load(p, __ATOMIC_RELAXED, __HIP_MEMORY_SCOPE_AGENT);
            }
            h_sh[j] = __uint_as_float((u32)pk);
            asm volatile("s_waitcnt lgkmcnt(0)" ::: "memory");   // wave-level fence
        }
        // ---- dot: row r, k in [o*32, o*32+32) ----
        float acc = 0.0f;
        {
            const float4* hvp = reinterpret_cast<const float4*>(h_sh + o*32);
            #pragma unroll
            for (int i = 0; i < 8; ++i){
                float4 wv = *reinterpret_cast<const float4*>(wbuf + ((r*1024 + (o*8+i)*16) ^ ((r&7)<<4)));
                float4 hv = hvp[i];
                acc = fmaf(wv.x, hv.x, fmaf(wv.y, hv.y, fmaf(wv.z, hv.z, fmaf(wv.w, hv.w, acc))));
            }
        }
        partial[par*256 + o*32 + r] = acc;
        __syncthreads();              // the ONLY barrier per step
        if (j < 32){                  // wave 0: wave-parallel gates
            float s = xgc;
            #pragma unroll
            for (int oo = 0; oo < 8; ++oo) s += partial[par*256 + oo*32 + j];
            const float val = (g_r == 2) ? tanhf(s) : sigf(s);
            const float f_ = __shfl(val,  8 + u_r, 64);
            const float g_ = __shfl(val, 16 + u_r, 64);
            const float o_ = __shfl(val, 24 + u_r, 64);
            if (j < 8){
                c = f_*c + val*g_;                // val = i-gate for lanes 0..7
                const float h = o_*tanhf(c);
                const int ug = ulo + j;
                const u64 pk = ((u64)(u32)(t+1) << 32) | (u64)__float_as_uint(h);
                __hip_atomic_store(&hb[(size_t)((t+1)&1)*HDIM + ug], pk,
                                   __ATOMIC_RELAXED, __HIP_MEMORY_SCOPE_AGENT);
                hs[(size_t)(d==0 ? t : (T_LEN-1-t))*HDIM + ug] = h;
            }
            if (t+1 < T_LEN) xgc = xg[(size_t)(t+1)*G4 + row_global];  // prefetch
        }
    }
}

// ---------------------------------------------------------------------------
// K3: feats[t][tag] = [hf[t]; hb[t]] . W_out[tag] + b_out[tag]  (f32)
// ---------------------------------------------------------------------------
__global__ __launch_bounds__(256) void k_feats(
    const float* __restrict__ hs_f, const float* __restrict__ hs_b,
    const float* __restrict__ W_out, const float* __restrict__ b_out,
    float* __restrict__ feats)
{
    __shared__ __align__(16) float fsh[8][512];
    const int tb = blockIdx.x, j = threadIdx.x;
    #pragma unroll
    for (int r=0;r<8;++r){
        const int t = tb*8 + r;
        fsh[r][j]       = hs_f[(size_t)t*HDIM + j];
        fsh[r][256 + j] = hs_b[(size_t)t*HDIM + j];
    }
    __syncthreads();
    const int tsub = j >> 5, tag = j & 31;
    const float4* wr = reinterpret_cast<const float4*>(W_out + (size_t)tag*512);
    float acc = b_out[tag];
    for (int kk=0; kk<128; ++kk){
        float4 wvv = wr[kk];
        float4 hv = reinterpret_cast<const float4*>(fsh[tsub])[kk];
        acc = fmaf(wvv.x, hv.x, fmaf(wvv.y, hv.y, fmaf(wvv.z, hv.z, fmaf(wvv.w, hv.w, acc))));
    }
    feats[(size_t)(tb*8+tsub)*NTAGS + tag] = acc;
}

// ---------------------------------------------------------------------------
// K4a: Viterbi pass A — chunk transfer matrices G_c[n][q] via 32 basis-
// seeded 64-step scans per chunk (value-only; max is order-symmetric).
// ---------------------------------------------------------------------------
__global__ __launch_bounds__(256,1) void k_vitA(
    const float* __restrict__ feats, const float* __restrict__ trans,
    float* __restrict__ G)
{
    const int chunk = blockIdx.x >> 3;
    const int sg    = blockIdx.x & 7;
    const int w = threadIdx.x >> 6;
    const int l = threadIdx.x & 63;
    const int q = sg*4 + w;           // seed index 0..31
    const int n = l & 31, ph = (l >> 5) & 1;
    __shared__ float fv_sh[4][NTAGS];
    float tr[16];
    #pragma unroll
    for (int i=0;i<16;++i) tr[i] = trans[n*NTAGS + ph*16 + i];
    float fv = (n == q) ? 0.0f : -1e9f;   // max-plus basis vector
    const int t0 = chunk*64;
    for (int s = 0; s < 64; ++s){
        const float f = feats[(size_t)(t0+s)*NTAGS + n];
        if (ph == 0) fv_sh[w][n] = fv;    // same-wave lockstep publish
        float bestv = -1e30f;
        #pragma unroll
        for (int i=0;i<16;++i){
            const float v = fv_sh[w][ph*16 + i] + tr[i];
            if (v > bestv) bestv = v;
        }
        const float ov = __shfl_xor(bestv, 32, 64);
        fv = fmaxf(bestv, ov) + f;
    }
    if (ph == 0) G[((size_t)chunk*NTAGS + n)*NTAGS + q] = fv;
}

// ---------------------------------------------------------------------------
// K4b: Viterbi pass B — sequential seed composition (1 block).
// ---------------------------------------------------------------------------
__global__ __launch_bounds__(256,1) void k_vitB(
    const float* __restrict__ G, float* __restrict__ seeds)
{
    __shared__ float Gs[NTAGS*33];    // padded: bank = (row+col)&31
    __shared__ float s_sh[NTAGS];
    const int j = threadIdx.x;
    if (j < NTAGS){
        const float s0 = (j == START_TAG) ? 0.0f : -10000.0f;
        s_sh[j] = s0;
        seeds[j] = s0;
    }
    __syncthreads();
    for (int c = 0; c < 64; ++c){
        for (int idx = j; idx < NTAGS*NTAGS; idx += 256)
            Gs[(idx >> 5)*33 + (idx & 31)] = G[(size_t)c*NTAGS*NTAGS + idx];
        __syncthreads();
        float nv = 0.0f;
        if (j < NTAGS){
            float b = -1e30f;
            #pragma unroll
            for (int qq = 0; qq < NTAGS; ++qq)
                b = fmaxf(b, Gs[j*33 + qq] + s_sh[qq]);
            nv = b;
        }
        __syncthreads();              // all Gs/s_sh reads done
        if (j < NTAGS){
            s_sh[j] = nv;
            seeds[(size_t)(c+1)*NTAGS + j] = nv;
        }
        __syncthreads();
    }
}

// ---------------------------------------------------------------------------
// K4c: Viterbi pass C — per-chunk bp-emitting scan from exact seeds.
// ---------------------------------------------------------------------------
__global__ __launch_bounds__(64,1) void k_vitC(
    const float* __restrict__ feats, const float* __restrict__ trans,
    const float* __restrict__ seeds, unsigned char* __restrict__ bp_g)
{
    const int chunk = blockIdx.x;
    const int l = threadIdx.x;
    const int n = l & 31, ph = (l >> 5) & 1;
    __shared__ float fv_sh[NTAGS];
    float tr[16];
    #pragma unroll
    for (int i=0;i<16;++i) tr[i] = trans[n*NTAGS + ph*16 + i];
    float fv = seeds[(size_t)chunk*NTAGS + n];
    const int t0 = chunk*64;
    for (int s = 0; s < 64; ++s){
        const int t = t0 + s;
        const float f = feats[(size_t)t*NTAGS + n];
        if (ph == 0) fv_sh[n] = fv;
        float bestv = -1e30f; int bestp = 0;
        #pragma unroll
        for (int i=0;i<16;++i){
            const int p = ph*16 + i;
            const float v = fv_sh[p] + tr[i];
            if (v > bestv){ bestv = v; bestp = p; }   // strict > = first index
        }
        const float ov = __shfl_xor(bestv, 32, 64);
        const int   op = __shfl_xor(bestp, 32, 64);
        const float lowv  = ph ? ov    : bestv;
        const int   lowp  = ph ? op    : bestp;
        const float highv = ph ? bestv : ov;
        const int   highp = ph ? bestp : op;
        float wvv = lowv; int wp = lowp;
        if (highv > lowv){ wvv = highv; wp = highp; }  // low half wins ties
        if (ph == 0) bp_g[(size_t)t*NTAGS + n] = (unsigned char)wp;
        fv = wvv + f;
    }
}

// ---------------------------------------------------------------------------
// K4d: terminal + serial backtrace (uses seeds[64] as terminal fv).
// ---------------------------------------------------------------------------
__global__ __launch_bounds__(256,1) void k_vitD(
    const float* __restrict__ seeds, const float* __restrict__ trans,
    const unsigned char* __restrict__ bp_g, float* __restrict__ out)
{
    __shared__ __align__(16) char bp_sh[32*1024];   // 1024-step bp chunks
    __shared__ float term_sh[NTAGS];
    __shared__ int best_sh;
    const int j = threadIdx.x;
    if (j < NTAGS) term_sh[j] = seeds[(size_t)64*NTAGS + j] + trans[STOP_TAG*NTAGS + j];
    __syncthreads();
    if (j == 0){
        float bv = term_sh[0]; int bi = 0;
        for (int p = 1; p < NTAGS; ++p){
            if (term_sh[p] > bv){ bv = term_sh[p]; bi = p; }
        }
        out[0] = bv;
        out[1 + (T_LEN-1)] = (float)bi;
        best_sh = bi;
    }
    __syncthreads();
    int b = best_sh;
    for (int cc2 = 3; cc2 >= 0; --cc2){
        const u32* src = reinterpret_cast<const u32*>(bp_g + (size_t)cc2*1024*NTAGS);
        u32* dst = reinterpret_cast<u32*>(bp_sh);
        for (int idx = j; idx < 8192; idx += 256) dst[idx] = src[idx];
        __syncthreads();
        if (j == 0){
            for (int tt = 1023; tt >= 0; --tt){
                const int t = cc2*1024 + tt;
                if (t == 0) break;                 // step into <START> dropped
                const int nb2 = bp_sh[tt*NTAGS + b];
                out[1 + (t-1)] = (float)nb2;
                b = nb2;
            }
        }
        __syncthreads();
    }
}

// ---------------------------------------------------------------------------
extern "C" void kernel_launch(void* const* d_in, const int* in_sizes, int n_in,
                              void* d_out, int out_size, void* d_ws, size_t ws_size,
                              hipStream_t stream)
{
    const int*   seq   = (const int*)  d_in[0];
    const float* E     = (const float*)d_in[1];
    const float* Wih_f = (const float*)d_in[2];
    const float* Whh_f = (const float*)d_in[3];
    const float* bih_f = (const float*)d_in[4];
    const float* bhh_f = (const float*)d_in[5];
    const float* Wih_b = (const float*)d_in[6];
    const float* Whh_b = (const float*)d_in[7];
    const float* bih_b = (const float*)d_in[8];
    const float* bhh_b = (const float*)d_in[9];
    const float* h0    = (const float*)d_in[10];
    const float* c0    = (const float*)d_in[11];
    const float* W_out = (const float*)d_in[12];
    const float* b_out = (const float*)d_in[13];
    const float* trans = (const float*)d_in[14];

    char* ws = (char*)d_ws;
    float* xg_f  = (float*)(ws);                                 // 16 MB
    float* xg_b  = (float*)(ws + (size_t)(16u<<20));             // 16 MB
    float* hs_f  = (float*)(ws + (size_t)(32u<<20));             // 4 MB
    float* hs_b  = (float*)(ws + (size_t)(36u<<20));             // 4 MB
    float* feats = (float*)(ws + (size_t)(40u<<20));             // 512 KB
    unsigned char* bp = (unsigned char*)(ws + (size_t)(40u<<20) + (512u<<10)); // 128 KB
    u64* hbuf    = (u64*)(ws + (size_t)(40u<<20) + (640u<<10));  // 8 KB
    float* Gmat  = (float*)(ws + (size_t)(41u<<20));             // 256 KB
    float* seeds = (float*)(ws + (size_t)(41u<<20) + (256u<<10));// 8.3 KB

    k_xg<<<dim3(4096), dim3(256), 0, stream>>>(seq, E, Wih_f, bih_f, bhh_f,
                                               Wih_b, bih_b, bhh_b, xg_f, xg_b);
    k_lstm<<<dim3(64), dim3(256), 0, stream>>>(Whh_f, Whh_b, xg_f, xg_b, h0, c0, hs_f, hs_b, hbuf);
    k_feats<<<dim3(512), dim3(256), 0, stream>>>(hs_f, hs_b, W_out, b_out, feats);
    k_vitA<<<dim3(512), dim3(256), 0, stream>>>(feats, trans, Gmat);
    k_vitB<<<dim3(1),   dim3(256), 0, stream>>>(Gmat, seeds);
    k_vitC<<<dim3(64),  dim3(64),  0, stream>>>(feats, trans, seeds, bp);
    k_vitD<<<dim3(1),   dim3(256), 0, stream>>>(seeds, trans, bp, (float*)d_out);
}

// Round 15
// 6119.444 us; speedup vs baseline: 1.0290x; 1.0290x over previous
//
#include <hip/hip_runtime.h>
#include <hip/hip_bf16.h>
#include <stdint.h>

#define T_LEN 4096
#define D_DIM 256
#define HDIM 256
#define G4 1024          // 4*HD gate rows per direction
#define NTAGS 32
#define START_TAG 30
#define STOP_TAG 31

typedef unsigned long long u64;
typedef unsigned int u32;

__device__ __forceinline__ float sigf(float x){ return 1.0f/(1.0f+expf(-x)); }

// ---------------------------------------------------------------------------
// K1: embedding gather + input projections (r6-exact 4096-block version).
// ---------------------------------------------------------------------------
__global__ __launch_bounds__(256) void k_xg(const int* __restrict__ seq,
    const float* __restrict__ E,
    const float* __restrict__ Wf, const float* __restrict__ bihf, const float* __restrict__ bhhf,
    const float* __restrict__ Wb, const float* __restrict__ bihb, const float* __restrict__ bhhb,
    float* __restrict__ xg_f, float* __restrict__ xg_b)
{
    __shared__ __align__(16) float xsh[8][D_DIM];
    __shared__ int sq[8];
    const int b = blockIdx.x, tb = b >> 3, cb = b & 7, j = threadIdx.x;
    if (j < 8) sq[j] = seq[tb*8 + j];
    __syncthreads();
    #pragma unroll
    for (int r = 0; r < 8; ++r) xsh[r][j] = E[(size_t)sq[r]*D_DIM + j];
    __syncthreads();
    const int col = cb*256 + j;      // 0..2047
    const int d   = col >> 10;       // 0 fwd, 1 bwd
    const int row = col & 1023;
    const float* W = d ? Wb : Wf;
    const float bias = d ? (bihb[row] + bhhb[row]) : (bihf[row] + bhhf[row]);
    const float4* wr = reinterpret_cast<const float4*>(W + (size_t)row*D_DIM);
    float acc[8];
    #pragma unroll
    for (int r=0;r<8;++r) acc[r] = 0.f;
    for (int kk = 0; kk < D_DIM/4; ++kk){
        float4 wv = wr[kk];
        #pragma unroll
        for (int r=0;r<8;++r){
            float4 xv = reinterpret_cast<const float4*>(xsh[r])[kk];
            acc[r] = fmaf(wv.x, xv.x, fmaf(wv.y, xv.y, fmaf(wv.z, xv.z, fmaf(wv.w, xv.w, acc[r]))));
        }
    }
    #pragma unroll
    for (int r=0;r<8;++r){
        const int t = tb*8 + r;
        const float v = acc[r] + bias;
        if (d == 0) xg_f[(size_t)t*G4 + row] = v;
        else        xg_b[(size_t)(T_LEN-1-t)*G4 + row] = v;
    }
}

// ---------------------------------------------------------------------------
// K2: bidirectional LSTM — the r6/r13 kernel EXACTLY (established optimum:
// 4-wave TLP, one barrier/step, wave-private h slices, packed tag|h agent
// atomics, single-load tight poll). 14 rounds of probes: compute, LDS,
// weight delivery, topology, poll sampling all excluded; remaining cost is
// the LLC visibility round trip of the cross-CU h exchange.
// ---------------------------------------------------------------------------
__global__ __launch_bounds__(256,1) void k_lstm(
    const float* __restrict__ Whh_f, const float* __restrict__ Whh_b,
    const float* __restrict__ xgf, const float* __restrict__ xgb,
    const float* __restrict__ h0, const float* __restrict__ c0,
    float* __restrict__ hs_f, float* __restrict__ hs_b,
    u64* __restrict__ hbuf_all)
{
    const int blk = blockIdx.x;       // 0..63
    const int d   = blk >> 5;         // direction
    const int sb  = blk & 31;         // sub-block within direction
    const int ulo = sb * 8;           // first owned unit
    const int j = threadIdx.x;        // 0..255
    const int r = j & 31;             // row_local in [0,32)
    const int o = j >> 5;             // k-slice (32 k each)
    const int g_r = r >> 3;           // gate of this row
    const int u_r = r & 7;            // unit offset
    const int row_global = g_r*256 + ulo + u_r;   // in [0,1024)

    const float* __restrict__ Whh = d ? Whh_b : Whh_f;
    const float* __restrict__ xg  = d ? xgb : xgf;
    float* __restrict__ hs = d ? hs_b : hs_f;
    u64* __restrict__ hb = hbuf_all + (size_t)d*2*HDIM;   // [parity][unit]

    __shared__ __align__(16) char wbuf[32*1024];  // [r][k] f32, swizzled
    __shared__ float h_sh[HDIM];                  // wave w owns [64w,64w+64)
    __shared__ float partial[2*256];              // [parity][o][r]

    // ---- stage weights (thread stages exactly its read set) ----
    {
        const float4* src = reinterpret_cast<const float4*>(Whh + (size_t)row_global*HDIM + o*32);
        #pragma unroll
        for (int i = 0; i < 8; ++i){
            *reinterpret_cast<float4*>(wbuf + ((r*1024 + (o*8+i)*16) ^ ((r&7)<<4))) = src[i];
        }
    }
    h_sh[j] = h0[d*HDIM + j];
    float c = (j < 8) ? c0[d*HDIM + ulo + j] : 0.0f;
    float xgc = xg[row_global];       // xg[0][row]
    __syncthreads();

    for (int t = 0; t < T_LEN; ++t){
        const int par = t & 1;
        if (t > 0){
            // poll unit j (tag t): wave-private h slice, no barrier needed
            const u32 want = (u32)t;
            u64* p = &hb[(size_t)par*HDIM + j];
            u64 pk = __hip_atomic_load(p, __ATOMIC_RELAXED, __HIP_MEMORY_SCOPE_AGENT);
            while ((u32)(pk >> 32) != want)
                pk = __hip_atomic_load(p, __ATOMIC_RELAXED, __HIP_MEMORY_SCOPE_AGENT);
            h_sh[j] = __uint_as_float((u32)pk);
            asm volatile("s_waitcnt lgkmcnt(0)" ::: "memory");   // wave-level fence
        }
        // ---- dot: row r, k in [o*32, o*32+32) ----
        float acc = 0.0f;
        {
            const float4* hvp = reinterpret_cast<const float4*>(h_sh + o*32);
            #pragma unroll
            for (int i = 0; i < 8; ++i){
                float4 wv = *reinterpret_cast<const float4*>(wbuf + ((r*1024 + (o*8+i)*16) ^ ((r&7)<<4)));
                float4 hv = hvp[i];
                acc = fmaf(wv.x, hv.x, fmaf(wv.y, hv.y, fmaf(wv.z, hv.z, fmaf(wv.w, hv.w, acc))));
            }
        }
        partial[par*256 + o*32 + r] = acc;
        __syncthreads();              // the ONLY barrier per step
        if (j < 32){                  // wave 0: wave-parallel gates
            float s = xgc;
            #pragma unroll
            for (int oo = 0; oo < 8; ++oo) s += partial[par*256 + oo*32 + j];
            const float val = (g_r == 2) ? tanhf(s) : sigf(s);
            const float f_ = __shfl(val,  8 + u_r, 64);
            const float g_ = __shfl(val, 16 + u_r, 64);
            const float o_ = __shfl(val, 24 + u_r, 64);
            if (j < 8){
                c = f_*c + val*g_;                // val = i-gate for lanes 0..7
                const float h = o_*tanhf(c);
                const int ug = ulo + j;
                const u64 pk = ((u64)(u32)(t+1) << 32) | (u64)__float_as_uint(h);
                __hip_atomic_store(&hb[(size_t)((t+1)&1)*HDIM + ug], pk,
                                   __ATOMIC_RELAXED, __HIP_MEMORY_SCOPE_AGENT);
                hs[(size_t)(d==0 ? t : (T_LEN-1-t))*HDIM + ug] = h;
            }
            if (t+1 < T_LEN) xgc = xg[(size_t)(t+1)*G4 + row_global];  // prefetch
        }
    }
}

// ---------------------------------------------------------------------------
// K3: feats[t][tag] = [hf[t]; hb[t]] . W_out[tag] + b_out[tag]  (f32)
// ---------------------------------------------------------------------------
__global__ __launch_bounds__(256) void k_feats(
    const float* __restrict__ hs_f, const float* __restrict__ hs_b,
    const float* __restrict__ W_out, const float* __restrict__ b_out,
    float* __restrict__ feats)
{
    __shared__ __align__(16) float fsh[8][512];
    const int tb = blockIdx.x, j = threadIdx.x;
    #pragma unroll
    for (int r=0;r<8;++r){
        const int t = tb*8 + r;
        fsh[r][j]       = hs_f[(size_t)t*HDIM + j];
        fsh[r][256 + j] = hs_b[(size_t)t*HDIM + j];
    }
    __syncthreads();
    const int tsub = j >> 5, tag = j & 31;
    const float4* wr = reinterpret_cast<const float4*>(W_out + (size_t)tag*512);
    float acc = b_out[tag];
    for (int kk=0; kk<128; ++kk){
        float4 wvv = wr[kk];
        float4 hv = reinterpret_cast<const float4*>(fsh[tsub])[kk];
        acc = fmaf(wvv.x, hv.x, fmaf(wvv.y, hv.y, fmaf(wvv.z, hv.z, fmaf(wvv.w, hv.w, acc))));
    }
    feats[(size_t)(tb*8+tsub)*NTAGS + tag] = acc;
}

// ---------------------------------------------------------------------------
// K4a: Viterbi pass A — chunk transfer matrices G_c[n][q] via 32 basis-
// seeded 64-step scans per chunk (value-only; max is order-symmetric).
// ---------------------------------------------------------------------------
__global__ __launch_bounds__(256,1) void k_vitA(
    const float* __restrict__ feats, const float* __restrict__ trans,
    float* __restrict__ G)
{
    const int chunk = blockIdx.x >> 3;
    const int sg    = blockIdx.x & 7;
    const int w = threadIdx.x >> 6;
    const int l = threadIdx.x & 63;
    const int q = sg*4 + w;           // seed index 0..31
    const int n = l & 31, ph = (l >> 5) & 1;
    __shared__ float fv_sh[4][NTAGS];
    float tr[16];
    #pragma unroll
    for (int i=0;i<16;++i) tr[i] = trans[n*NTAGS + ph*16 + i];
    float fv = (n == q) ? 0.0f : -1e9f;   // max-plus basis vector
    const int t0 = chunk*64;
    for (int s = 0; s < 64; ++s){
        const float f = feats[(size_t)(t0+s)*NTAGS + n];
        if (ph == 0) fv_sh[w][n] = fv;    // same-wave lockstep publish
        float bestv = -1e30f;
        #pragma unroll
        for (int i=0;i<16;++i){
            const float v = fv_sh[w][ph*16 + i] + tr[i];
            if (v > bestv) bestv = v;
        }
        const float ov = __shfl_xor(bestv, 32, 64);
        fv = fmaxf(bestv, ov) + f;
    }
    if (ph == 0) G[((size_t)chunk*NTAGS + n)*NTAGS + q] = fv;
}

// ---------------------------------------------------------------------------
// K4b: Viterbi pass B — sequential seed composition (1 block).
// ---------------------------------------------------------------------------
__global__ __launch_bounds__(256,1) void k_vitB(
    const float* __restrict__ G, float* __restrict__ seeds)
{
    __shared__ float Gs[NTAGS*33];    // padded: bank = (row+col)&31
    __shared__ float s_sh[NTAGS];
    const int j = threadIdx.x;
    if (j < NTAGS){
        const float s0 = (j == START_TAG) ? 0.0f : -10000.0f;
        s_sh[j] = s0;
        seeds[j] = s0;
    }
    __syncthreads();
    for (int c = 0; c < 64; ++c){
        for (int idx = j; idx < NTAGS*NTAGS; idx += 256)
            Gs[(idx >> 5)*33 + (idx & 31)] = G[(size_t)c*NTAGS*NTAGS + idx];
        __syncthreads();
        float nv = 0.0f;
        if (j < NTAGS){
            float b = -1e30f;
            #pragma unroll
            for (int qq = 0; qq < NTAGS; ++qq)
                b = fmaxf(b, Gs[j*33 + qq] + s_sh[qq]);
            nv = b;
        }
        __syncthreads();              // all Gs/s_sh reads done
        if (j < NTAGS){
            s_sh[j] = nv;
            seeds[(size_t)(c+1)*NTAGS + j] = nv;
        }
        __syncthreads();
    }
}

// ---------------------------------------------------------------------------
// K4c: Viterbi pass C — per-chunk bp-emitting scan from exact seeds.
// ---------------------------------------------------------------------------
__global__ __launch_bounds__(64,1) void k_vitC(
    const float* __restrict__ feats, const float* __restrict__ trans,
    const float* __restrict__ seeds, unsigned char* __restrict__ bp_g)
{
    const int chunk = blockIdx.x;
    const int l = threadIdx.x;
    const int n = l & 31, ph = (l >> 5) & 1;
    __shared__ float fv_sh[NTAGS];
    float tr[16];
    #pragma unroll
    for (int i=0;i<16;++i) tr[i] = trans[n*NTAGS + ph*16 + i];
    float fv = seeds[(size_t)chunk*NTAGS + n];
    const int t0 = chunk*64;
    for (int s = 0; s < 64; ++s){
        const int t = t0 + s;
        const float f = feats[(size_t)t*NTAGS + n];
        if (ph == 0) fv_sh[n] = fv;
        float bestv = -1e30f; int bestp = 0;
        #pragma unroll
        for (int i=0;i<16;++i){
            const int p = ph*16 + i;
            const float v = fv_sh[p] + tr[i];
            if (v > bestv){ bestv = v; bestp = p; }   // strict > = first index
        }
        const float ov = __shfl_xor(bestv, 32, 64);
        const int   op = __shfl_xor(bestp, 32, 64);
        const float lowv  = ph ? ov    : bestv;
        const int   lowp  = ph ? op    : bestp;
        const float highv = ph ? bestv : ov;
        const int   highp = ph ? bestp : op;
        float wvv = lowv; int wp = lowp;
        if (highv > lowv){ wvv = highv; wp = highp; }  // low half wins ties
        if (ph == 0) bp_g[(size_t)t*NTAGS + n] = (unsigned char)wp;
        fv = wvv + f;
    }
}

// ---------------------------------------------------------------------------
// K4d: terminal + serial backtrace (uses seeds[64] as terminal fv).
// ---------------------------------------------------------------------------
__global__ __launch_bounds__(256,1) void k_vitD(
    const float* __restrict__ seeds, const float* __restrict__ trans,
    const unsigned char* __restrict__ bp_g, float* __restrict__ out)
{
    __shared__ __align__(16) char bp_sh[32*1024];   // 1024-step bp chunks
    __shared__ float term_sh[NTAGS];
    __shared__ int best_sh;
    const int j = threadIdx.x;
    if (j < NTAGS) term_sh[j] = seeds[(size_t)64*NTAGS + j] + trans[STOP_TAG*NTAGS + j];
    __syncthreads();
    if (j == 0){
        float bv = term_sh[0]; int bi = 0;
        for (int p = 1; p < NTAGS; ++p){
            if (term_sh[p] > bv){ bv = term_sh[p]; bi = p; }
        }
        out[0] = bv;
        out[1 + (T_LEN-1)] = (float)bi;
        best_sh = bi;
    }
    __syncthreads();
    int b = best_sh;
    for (int cc2 = 3; cc2 >= 0; --cc2){
        const u32* src = reinterpret_cast<const u32*>(bp_g + (size_t)cc2*1024*NTAGS);
        u32* dst = reinterpret_cast<u32*>(bp_sh);
        for (int idx = j; idx < 8192; idx += 256) dst[idx] = src[idx];
        __syncthreads();
        if (j == 0){
            for (int tt = 1023; tt >= 0; --tt){
                const int t = cc2*1024 + tt;
                if (t == 0) break;                 // step into <START> dropped
                const int nb2 = bp_sh[tt*NTAGS + b];
                out[1 + (t-1)] = (float)nb2;
                b = nb2;
            }
        }
        __syncthreads();
    }
}

// ---------------------------------------------------------------------------
extern "C" void kernel_launch(void* const* d_in, const int* in_sizes, int n_in,
                              void* d_out, int out_size, void* d_ws, size_t ws_size,
                              hipStream_t stream)
{
    const int*   seq   = (const int*)  d_in[0];
    const float* E     = (const float*)d_in[1];
    const float* Wih_f = (const float*)d_in[2];
    const float* Whh_f = (const float*)d_in[3];
    const float* bih_f = (const float*)d_in[4];
    const float* bhh_f = (const float*)d_in[5];
    const float* Wih_b = (const float*)d_in[6];
    const float* Whh_b = (const float*)d_in[7];
    const float* bih_b = (const float*)d_in[8];
    const float* bhh_b = (const float*)d_in[9];
    const float* h0    = (const float*)d_in[10];
    const float* c0    = (const float*)d_in[11];
    const float* W_out = (const float*)d_in[12];
    const float* b_out = (const float*)d_in[13];
    const float* trans = (const float*)d_in[14];

    char* ws = (char*)d_ws;
    float* xg_f  = (float*)(ws);                                 // 16 MB
    float* xg_b  = (float*)(ws + (size_t)(16u<<20));             // 16 MB
    float* hs_f  = (float*)(ws + (size_t)(32u<<20));             // 4 MB
    float* hs_b  = (float*)(ws + (size_t)(36u<<20));             // 4 MB
    float* feats = (float*)(ws + (size_t)(40u<<20));             // 512 KB
    unsigned char* bp = (unsigned char*)(ws + (size_t)(40u<<20) + (512u<<10)); // 128 KB
    u64* hbuf    = (u64*)(ws + (size_t)(40u<<20) + (640u<<10));  // 8 KB
    float* Gmat  = (float*)(ws + (size_t)(41u<<20));             // 256 KB
    float* seeds = (float*)(ws + (size_t)(41u<<20) + (256u<<10));// 8.3 KB

    k_xg<<<dim3(4096), dim3(256), 0, stream>>>(seq, E, Wih_f, bih_f, bhh_f,
                                               Wih_b, bih_b, bhh_b, xg_f, xg_b);
    k_lstm<<<dim3(64), dim3(256), 0, stream>>>(Whh_f, Whh_b, xg_f, xg_b, h0, c0, hs_f, hs_b, hbuf);
    k_feats<<<dim3(512), dim3(256), 0, stream>>>(hs_f, hs_b, W_out, b_out, feats);
    k_vitA<<<dim3(512), dim3(256), 0, stream>>>(feats, trans, Gmat);
    k_vitB<<<dim3(1),   dim3(256), 0, stream>>>(Gmat, seeds);
    k_vitC<<<dim3(64),  dim3(64),  0, stream>>>(feats, trans, seeds, bp);
    k_vitD<<<dim3(1),   dim3(256), 0, stream>>>(seeds, trans, bp, (float*)d_out);
}